// Round 14
// baseline (248.619 us; speedup 1.0000x reference)
//
#include <hip/hip_runtime.h>
#include <hip/hip_bf16.h>
#include <hip/hip_cooperative_groups.h>
#include <cstdint>

namespace cg = cooperative_groups;

typedef __attribute__((ext_vector_type(8))) short bf16x8;
typedef __attribute__((ext_vector_type(4))) float f32x4;

__device__ __forceinline__ float lrelu02(float x){ return x > 0.f ? x : 0.2f*x; }
__device__ __forceinline__ float elu1(float x){ return x > 0.f ? x : __expf(x)-1.f; }
__device__ __forceinline__ unsigned short bf16_rne(float f){
  unsigned int u = __float_as_uint(f);
  u += 0x7FFFu + ((u >> 16) & 1u);
  return (unsigned short)(u >> 16);
}
__device__ __forceinline__ float b2f(unsigned int hi16){ return __uint_as_float(hi16 << 16); }
__device__ __forceinline__ unsigned int packbf(float a, float b){
  return (unsigned int)bf16_rne(a) | ((unsigned int)bf16_rne(b) << 16);
}

// ---------------- cooperative CSR build: hist + scan + fill, 2 grid syncs ----------------
__global__ void csr_kernel(const int* __restrict__ ei, int* __restrict__ cnt,
                           int* __restrict__ rp, int* __restrict__ fl,
                           int* __restrict__ col, int E, int N){
  cg::grid_group grid = cg::this_grid();
  int tid = blockIdx.x*blockDim.x + threadIdx.x;
  int nth = gridDim.x*blockDim.x;
  // phase 1: histogram (cnt pre-zeroed by conv_all)
  for (int e = tid; e < E; e += nth) atomicAdd(&cnt[ei[E + e]], 1);
  grid.sync();
  // phase 2: exclusive scan by block 0 (256 thr x PER=40 covers N=10000)
  if (blockIdx.x == 0){
    __shared__ int part[256];
    const int PER = 40;
    int t = threadIdx.x;
    int base = t*PER;
    int local[PER]; int s = 0;
    #pragma unroll
    for (int i=0;i<PER;i++){ int idx=base+i; int v = (idx<N)? cnt[idx] : 0; local[i]=s; s+=v; }
    part[t]=s; __syncthreads();
    for (int off=1; off<256; off<<=1){
      int v = (t>=off)? part[t-off] : 0;
      __syncthreads();
      part[t] += v;
      __syncthreads();
    }
    int ex = (t>0)? part[t-1] : 0;
    #pragma unroll
    for (int i=0;i<PER;i++){ int idx=base+i; if (idx<N) rp[idx] = ex + local[i]; }
    if (t==0) rp[N] = part[255];
  }
  grid.sync();
  // phase 3: fill
  for (int e = tid; e < E; e += nth){
    int d = ei[E + e];
    int pos = rp[d] + atomicAdd(&fl[d], 1);
    col[pos] = ei[e];
  }
}

// ---------------- fused conversions + cnt/fl zeroing ----------------
__global__ void conv_all_kernel(const float* __restrict__ x, unsigned short* __restrict__ xb,
                                const float* __restrict__ W1, unsigned short* __restrict__ W1t,
                                const float* __restrict__ W2, unsigned short* __restrict__ W2t,
                                const float* __restrict__ mw1, unsigned short* __restrict__ mw1t,
                                int* __restrict__ zbase, int nz){
  int t = blockIdx.x*256 + threadIdx.x;
  if (t < 320000){
    int i = t*4;
    float4 v = *(const float4*)(x + i);
    xb[i+0] = bf16_rne(v.x); xb[i+1] = bf16_rne(v.y);
    xb[i+2] = bf16_rne(v.z); xb[i+3] = bf16_rne(v.w);
  } else if (t < 385536){
    int i = t - 320000;                 // W1 [128][512] -> W1t [512][128]
    int n = i >> 7, k = i & 127;
    W1t[i] = bf16_rne(W1[(size_t)k*512 + n]);
  } else if (t < 451072){
    int i = t - 385536;                 // W2 [512][128] -> W2t [128][512]
    int n = i >> 9, k = i & 511;
    W2t[i] = bf16_rne(W2[(size_t)k*128 + n]);
  } else if (t < 461312){
    int i = t - 451072;                 // mw1 [144][64] -> mw1t [64][160] (pad)
    int n = i / 160, k = i % 160;
    mw1t[i] = (k < 144) ? bf16_rne(mw1[(size_t)k*64 + n]) : (unsigned short)0;
  } else if (t < 461312 + nz){
    zbase[t - 461312] = 0;
  }
}

// ---------------- MFMA bf16 GEMM: C = A[M,K] @ Bt[N,K]^T ----------
template<int BN, int SPLITK, int RELU, int WB, int OUTB>
__global__ __launch_bounds__(256) void mgemm_kernel(
    const unsigned short* __restrict__ A,  // [M][K] bf16
    const unsigned short* __restrict__ Bt, // [N][K] bf16
    const float* __restrict__ bias,
    void* __restrict__ C,
    int M, int N, int K){
  const int BM = 128, BK = 32, LDP = BK + 8;
  const int NF = BN/32;
  __shared__ unsigned short As[BM*LDP];
  __shared__ unsigned short Bs[BN*LDP];
  int tid = threadIdx.x;
  int lane = tid & 63, wid = tid >> 6;
  int wr = wid >> 1, wc = wid & 1;
  int row0 = blockIdx.y*BM, col0 = blockIdx.x*BN;
  int kchunk = K / SPLITK;
  int k0base = blockIdx.z * kchunk;
  f32x4 acc[4][NF];
  #pragma unroll
  for (int m=0;m<4;m++)
    #pragma unroll
    for (int n=0;n<NF;n++) acc[m][n] = (f32x4){0.f,0.f,0.f,0.f};

  for (int kt = 0; kt < kchunk; kt += BK){
    int k0 = k0base + kt;
    #pragma unroll
    for (int i=0;i<(BM*4)/256;i++){
      int li = i*256 + tid;
      int r = li >> 2, q = li & 3;
      int gr = row0 + r;
      uint4 v = make_uint4(0u,0u,0u,0u);
      if (gr < M) v = *(const uint4*)(A + (size_t)gr*K + k0 + q*8);
      *(uint4*)(&As[r*LDP + q*8]) = v;
    }
    #pragma unroll
    for (int i=0;i<(BN*4)/256;i++){
      int li = i*256 + tid;
      int r = li >> 2, q = li & 3;
      int gn = col0 + r;
      uint4 v = make_uint4(0u,0u,0u,0u);
      if (gn < N) v = *(const uint4*)(Bt + (size_t)gn*K + k0 + q*8);
      *(uint4*)(&Bs[r*LDP + q*8]) = v;
    }
    __syncthreads();
    int kq = (lane >> 4) * 8;
    bf16x8 af[4], bfr[NF];
    #pragma unroll
    for (int m=0;m<4;m++)
      af[m] = *(const bf16x8*)(&As[(wr*64 + m*16 + (lane&15))*LDP + kq]);
    #pragma unroll
    for (int n=0;n<NF;n++)
      bfr[n] = *(const bf16x8*)(&Bs[(wc*(BN/2) + n*16 + (lane&15))*LDP + kq]);
    #pragma unroll
    for (int m=0;m<4;m++)
      #pragma unroll
      for (int n=0;n<NF;n++)
        acc[m][n] = __builtin_amdgcn_mfma_f32_16x16x32_bf16(af[m], bfr[n], acc[m][n], 0, 0, 0);
    __syncthreads();
  }
  #pragma unroll
  for (int m=0;m<4;m++){
    #pragma unroll
    for (int j=0;j<4;j++){
      int r = row0 + wr*64 + m*16 + (lane>>4)*4 + j;
      if (r >= M) continue;
      #pragma unroll
      for (int n=0;n<NF;n++){
        int c = col0 + wc*(BN/2) + n*16 + (lane&15);
        float v = acc[m][n][j];
        if (WB) v += bias[c];
        if (RELU) v = fmaxf(v, 0.f);
        if (OUTB){
          ((unsigned short*)C)[(size_t)r*N + c] = bf16_rne(v);
        } else {
          float* Cb = (float*)C + (size_t)blockIdx.z * M * N;
          Cb[(size_t)r*N + c] = v;
        }
      }
    }
  }
}

// ---------------- edge-MLP mega-kernel: feats-gather staging + GEMM + LDS-tile final layer
__global__ __launch_bounds__(256) void mgemm_mlp2_kernel(
    const unsigned short* __restrict__ hf,   // out2b [N][128] bf16
    const int* __restrict__ eli,             // [2][M]
    const float* __restrict__ attr,          // [M][16]
    const unsigned short* __restrict__ Bt,   // mw1t [64][160] bf16
    const float* __restrict__ mb1,
    const float* __restrict__ w2,            // [64][2]
    const float* __restrict__ b2,            // [2]
    float* __restrict__ out, int M){
  const int BK = 32, LDP = BK + 8, K = 160;
  __shared__ unsigned short As[128*LDP];
  __shared__ unsigned short Bs[64*LDP];
  __shared__ float hid[128][65];
  __shared__ float w2s[128];
  int tid = threadIdx.x;
  int lane = tid & 63, wid = tid >> 6;
  int wr = wid >> 1, wc = wid & 1;
  int row0 = blockIdx.y*128;
  if (tid < 128) w2s[tid] = w2[tid];

  int r0_ = tid >> 2, q_ = tid & 3;
  int r1_ = 64 + r0_;
  int gr0 = row0 + r0_, gr1 = row0 + r1_;
  bool ok0 = gr0 < M, ok1 = gr1 < M;
  int s0=0, d0=0, s1=0, d1=0;
  if (ok0){ s0 = eli[gr0]; d0 = eli[M + gr0]; }
  if (ok1){ s1 = eli[gr1]; d1 = eli[M + gr1]; }

  auto make_chunk = [&](int s, int d, int gr, bool ok, int k) -> uint4 {
    uint4 v = make_uint4(0u,0u,0u,0u);
    if (!ok) return v;
    if (k < 128){
      uint4 a = *(const uint4*)(hf + (size_t)s*128 + k);
      uint4 b = *(const uint4*)(hf + (size_t)d*128 + k);
      v.x = packbf(b2f(a.x & 0xffffu)*b2f(b.x & 0xffffu), b2f(a.x >> 16)*b2f(b.x >> 16));
      v.y = packbf(b2f(a.y & 0xffffu)*b2f(b.y & 0xffffu), b2f(a.y >> 16)*b2f(b.y >> 16));
      v.z = packbf(b2f(a.z & 0xffffu)*b2f(b.z & 0xffffu), b2f(a.z >> 16)*b2f(b.z >> 16));
      v.w = packbf(b2f(a.w & 0xffffu)*b2f(b.w & 0xffffu), b2f(a.w >> 16)*b2f(b.w >> 16));
    } else if (k < 144){
      const float* pa = attr + (size_t)gr*16 + (k - 128);
      float4 x0 = *(const float4*)pa;
      float4 x1 = *(const float4*)(pa + 4);
      v.x = packbf(x0.x, x0.y); v.y = packbf(x0.z, x0.w);
      v.z = packbf(x1.x, x1.y); v.w = packbf(x1.z, x1.w);
    }
    return v;
  };

  f32x4 acc[4][2];
  #pragma unroll
  for (int m=0;m<4;m++){ acc[m][0] = (f32x4){0,0,0,0}; acc[m][1] = (f32x4){0,0,0,0}; }

  for (int k0 = 0; k0 < K; k0 += BK){
    int k = k0 + q_*8;
    *(uint4*)(&As[r0_*LDP + q_*8]) = make_chunk(s0, d0, gr0, ok0, k);
    *(uint4*)(&As[r1_*LDP + q_*8]) = make_chunk(s1, d1, gr1, ok1, k);
    {
      int r = tid >> 2, q = tid & 3;
      uint4 v = *(const uint4*)(Bt + (size_t)r*K + k0 + q*8);
      *(uint4*)(&Bs[r*LDP + q*8]) = v;
    }
    __syncthreads();
    int kq = (lane >> 4) * 8;
    bf16x8 af[4], bfr[2];
    #pragma unroll
    for (int m=0;m<4;m++)
      af[m] = *(const bf16x8*)(&As[(wr*64 + m*16 + (lane&15))*LDP + kq]);
    #pragma unroll
    for (int n=0;n<2;n++)
      bfr[n] = *(const bf16x8*)(&Bs[(wc*32 + n*16 + (lane&15))*LDP + kq]);
    #pragma unroll
    for (int m=0;m<4;m++)
      #pragma unroll
      for (int n=0;n<2;n++)
        acc[m][n] = __builtin_amdgcn_mfma_f32_16x16x32_bf16(af[m], bfr[n], acc[m][n], 0, 0, 0);
    __syncthreads();
  }
  // phase 2a: stage relu(acc + mb1) into LDS with the proven (r,c) mapping
  #pragma unroll
  for (int m=0;m<4;m++){
    #pragma unroll
    for (int j=0;j<4;j++){
      int r = wr*64 + m*16 + (lane>>4)*4 + j;
      #pragma unroll
      for (int n=0;n<2;n++){
        int c = wc*32 + n*16 + (lane&15);
        hid[r][c] = fmaxf(acc[m][n][j] + mb1[c], 0.f);
      }
    }
  }
  __syncthreads();
  // phase 2b: per-row dot with w2; thread t owns row t>>1, half t&1
  int r = tid >> 1, hf2 = tid & 1;
  int cbase = hf2*32;
  float p0 = 0.f, p1 = 0.f;
  #pragma unroll
  for (int c=0;c<32;c++){
    float v = hid[r][cbase + c];
    p0 += v * w2s[(cbase + c)*2 + 0];
    p1 += v * w2s[(cbase + c)*2 + 1];
  }
  p0 += __shfl_xor(p0, 1, 64);
  p1 += __shfl_xor(p1, 1, 64);
  if (hf2 == 0 && row0 + r < M){
    out[(size_t)(row0 + r)*2 + 0] = p0 + b2[0];
    out[(size_t)(row0 + r)*2 + 1] = p1 + b2[1];
  }
}

// sum 4 split-K partials -> bf16, fused layer-2 attention coefficients.
__global__ void reduce4b_attn_kernel(const float4* __restrict__ p, uint2* __restrict__ o,
                                     const float* __restrict__ as2, const float* __restrict__ ad2,
                                     float* __restrict__ asrc, float* __restrict__ adst,
                                     int N, int s4){
  int idx = blockIdx.x*256 + threadIdx.x;
  int n = idx >> 5;
  if (n >= N) return;
  float4 a = p[idx], b = p[idx+s4], c = p[idx+2*s4], d = p[idx+3*s4];
  float rx = a.x+b.x+c.x+d.x, ry = a.y+b.y+c.y+d.y;
  float rz = a.z+b.z+c.z+d.z, rw = a.w+b.w+c.w+d.w;
  o[idx] = make_uint2(packbf(rx, ry), packbf(rz, rw));
  int c4 = (idx & 31)*4;
  float ps = rx*as2[c4] + ry*as2[c4+1] + rz*as2[c4+2] + rw*as2[c4+3];
  float pd = rx*ad2[c4] + ry*ad2[c4+1] + rz*ad2[c4+2] + rw*ad2[c4+3];
  #pragma unroll
  for (int off=1; off<32; off<<=1){ ps += __shfl_xor(ps,off,64); pd += __shfl_xor(pd,off,64); }
  if ((idx & 31) == 0){ asrc[n] = ps; adst[n] = pd; }
}

// ---------------- layer-1 attention coefficients, head-merged: one wave per node
__global__ void attn4_kernel(const unsigned short* __restrict__ h,
                             const float* __restrict__ att_src,   // [512]
                             const float* __restrict__ att_dst,
                             float* __restrict__ asrc, float* __restrict__ adst, int N){
  int lane = threadIdx.x & 63;
  int n = blockIdx.x*4 + (threadIdx.x >> 6);
  if (n >= N) return;
  const uint4* hp = (const uint4*)(h + (size_t)n*512);
  uint4 u = hp[lane];
  int ch = lane*8;
  float f0 = b2f(u.x & 0xffffu), f1 = b2f(u.x >> 16);
  float f2 = b2f(u.y & 0xffffu), f3 = b2f(u.y >> 16);
  float f4 = b2f(u.z & 0xffffu), f5 = b2f(u.z >> 16);
  float f6 = b2f(u.w & 0xffffu), f7 = b2f(u.w >> 16);
  float s = f0*att_src[ch+0] + f1*att_src[ch+1] + f2*att_src[ch+2] + f3*att_src[ch+3]
          + f4*att_src[ch+4] + f5*att_src[ch+5] + f6*att_src[ch+6] + f7*att_src[ch+7];
  float d = f0*att_dst[ch+0] + f1*att_dst[ch+1] + f2*att_dst[ch+2] + f3*att_dst[ch+3]
          + f4*att_dst[ch+4] + f5*att_dst[ch+5] + f6*att_dst[ch+6] + f7*att_dst[ch+7];
  #pragma unroll
  for (int o=1; o<16; o<<=1){ s += __shfl_xor(s, o, 64); d += __shfl_xor(d, o, 64); }
  if ((lane & 15) == 0){
    int hh = lane >> 4;
    asrc[n*4 + hh] = s; adst[n*4 + hh] = d;
  }
}

// ---------------- layer-1 aggregation, head-merged single pass, 8-deep prefetch
__global__ void agg4_kernel(const unsigned short* __restrict__ h,   // [N][512]
                            const float* __restrict__ asrc,         // [N][4]
                            const float* __restrict__ adst,
                            const float* __restrict__ bias,         // [512]
                            const int* __restrict__ rp,
                            const int* __restrict__ col,
                            unsigned short* __restrict__ outb, int N){
  int lane = threadIdx.x & 63;
  int n = blockIdx.x*4 + (threadIdx.x >> 6);
  if (n >= N) return;
  int hh = lane >> 4;
  int beg = rp[n], end = rp[n+1];
  float adst_i = adst[n*4 + hh];
  float wself = __expf(lrelu02(asrc[n*4 + hh] + adst_i));
  const uint4* hp = (const uint4*)(h + (size_t)n*512);
  uint4 us = hp[lane];
  float a0 = b2f(us.x & 0xffffu)*wself, a1 = b2f(us.x >> 16)*wself;
  float a2 = b2f(us.y & 0xffffu)*wself, a3 = b2f(us.y >> 16)*wself;
  float a4 = b2f(us.z & 0xffffu)*wself, a5 = b2f(us.z >> 16)*wself;
  float a6 = b2f(us.w & 0xffffu)*wself, a7 = b2f(us.w >> 16)*wself;
  float wsum = wself;

  int e = beg;
  for (; e + 8 <= end; e += 8){
    int s0 = col[e],   s1 = col[e+1], s2 = col[e+2], s3 = col[e+3];
    int s4 = col[e+4], s5 = col[e+5], s6 = col[e+6], s7 = col[e+7];
    uint4 u0 = ((const uint4*)(h + (size_t)s0*512))[lane];
    uint4 u1 = ((const uint4*)(h + (size_t)s1*512))[lane];
    uint4 u2 = ((const uint4*)(h + (size_t)s2*512))[lane];
    uint4 u3 = ((const uint4*)(h + (size_t)s3*512))[lane];
    uint4 u4 = ((const uint4*)(h + (size_t)s4*512))[lane];
    uint4 u5 = ((const uint4*)(h + (size_t)s5*512))[lane];
    uint4 u6 = ((const uint4*)(h + (size_t)s6*512))[lane];
    uint4 u7 = ((const uint4*)(h + (size_t)s7*512))[lane];
    float w0 = __expf(lrelu02(asrc[s0*4 + hh] + adst_i));
    float w1 = __expf(lrelu02(asrc[s1*4 + hh] + adst_i));
    float w2 = __expf(lrelu02(asrc[s2*4 + hh] + adst_i));
    float w3 = __expf(lrelu02(asrc[s3*4 + hh] + adst_i));
    float w4 = __expf(lrelu02(asrc[s4*4 + hh] + adst_i));
    float w5 = __expf(lrelu02(asrc[s5*4 + hh] + adst_i));
    float w6 = __expf(lrelu02(asrc[s6*4 + hh] + adst_i));
    float w7 = __expf(lrelu02(asrc[s7*4 + hh] + adst_i));
    wsum += w0 + w1 + w2 + w3 + w4 + w5 + w6 + w7;
    a0 += b2f(u0.x & 0xffffu)*w0; a1 += b2f(u0.x >> 16)*w0;
    a2 += b2f(u0.y & 0xffffu)*w0; a3 += b2f(u0.y >> 16)*w0;
    a4 += b2f(u0.z & 0xffffu)*w0; a5 += b2f(u0.z >> 16)*w0;
    a6 += b2f(u0.w & 0xffffu)*w0; a7 += b2f(u0.w >> 16)*w0;
    a0 += b2f(u1.x & 0xffffu)*w1; a1 += b2f(u1.x >> 16)*w1;
    a2 += b2f(u1.y & 0xffffu)*w1; a3 += b2f(u1.y >> 16)*w1;
    a4 += b2f(u1.z & 0xffffu)*w1; a5 += b2f(u1.z >> 16)*w1;
    a6 += b2f(u1.w & 0xffffu)*w1; a7 += b2f(u1.w >> 16)*w1;
    a0 += b2f(u2.x & 0xffffu)*w2; a1 += b2f(u2.x >> 16)*w2;
    a2 += b2f(u2.y & 0xffffu)*w2; a3 += b2f(u2.y >> 16)*w2;
    a4 += b2f(u2.z & 0xffffu)*w2; a5 += b2f(u2.z >> 16)*w2;
    a6 += b2f(u2.w & 0xffffu)*w2; a7 += b2f(u2.w >> 16)*w2;
    a0 += b2f(u3.x & 0xffffu)*w3; a1 += b2f(u3.x >> 16)*w3;
    a2 += b2f(u3.y & 0xffffu)*w3; a3 += b2f(u3.y >> 16)*w3;
    a4 += b2f(u3.z & 0xffffu)*w3; a5 += b2f(u3.z >> 16)*w3;
    a6 += b2f(u3.w & 0xffffu)*w3; a7 += b2f(u3.w >> 16)*w3;
    a0 += b2f(u4.x & 0xffffu)*w4; a1 += b2f(u4.x >> 16)*w4;
    a2 += b2f(u4.y & 0xffffu)*w4; a3 += b2f(u4.y >> 16)*w4;
    a4 += b2f(u4.z & 0xffffu)*w4; a5 += b2f(u4.z >> 16)*w4;
    a6 += b2f(u4.w & 0xffffu)*w4; a7 += b2f(u4.w >> 16)*w4;
    a0 += b2f(u5.x & 0xffffu)*w5; a1 += b2f(u5.x >> 16)*w5;
    a2 += b2f(u5.y & 0xffffu)*w5; a3 += b2f(u5.y >> 16)*w5;
    a4 += b2f(u5.z & 0xffffu)*w5; a5 += b2f(u5.z >> 16)*w5;
    a6 += b2f(u5.w & 0xffffu)*w5; a7 += b2f(u5.w >> 16)*w5;
    a0 += b2f(u6.x & 0xffffu)*w6; a1 += b2f(u6.x >> 16)*w6;
    a2 += b2f(u6.y & 0xffffu)*w6; a3 += b2f(u6.y >> 16)*w6;
    a4 += b2f(u6.z & 0xffffu)*w6; a5 += b2f(u6.z >> 16)*w6;
    a6 += b2f(u6.w & 0xffffu)*w6; a7 += b2f(u6.w >> 16)*w6;
    a0 += b2f(u7.x & 0xffffu)*w7; a1 += b2f(u7.x >> 16)*w7;
    a2 += b2f(u7.y & 0xffffu)*w7; a3 += b2f(u7.y >> 16)*w7;
    a4 += b2f(u7.z & 0xffffu)*w7; a5 += b2f(u7.z >> 16)*w7;
    a6 += b2f(u7.w & 0xffffu)*w7; a7 += b2f(u7.w >> 16)*w7;
  }
  for (; e + 4 <= end; e += 4){
    int s0 = col[e], s1 = col[e+1], s2 = col[e+2], s3 = col[e+3];
    uint4 u0 = ((const uint4*)(h + (size_t)s0*512))[lane];
    uint4 u1 = ((const uint4*)(h + (size_t)s1*512))[lane];
    uint4 u2 = ((const uint4*)(h + (size_t)s2*512))[lane];
    uint4 u3 = ((const uint4*)(h + (size_t)s3*512))[lane];
    float w0 = __expf(lrelu02(asrc[s0*4 + hh] + adst_i));
    float w1 = __expf(lrelu02(asrc[s1*4 + hh] + adst_i));
    float w2 = __expf(lrelu02(asrc[s2*4 + hh] + adst_i));
    float w3 = __expf(lrelu02(asrc[s3*4 + hh] + adst_i));
    wsum += w0 + w1 + w2 + w3;
    a0 += b2f(u0.x & 0xffffu)*w0; a1 += b2f(u0.x >> 16)*w0;
    a2 += b2f(u0.y & 0xffffu)*w0; a3 += b2f(u0.y >> 16)*w0;
    a4 += b2f(u0.z & 0xffffu)*w0; a5 += b2f(u0.z >> 16)*w0;
    a6 += b2f(u0.w & 0xffffu)*w0; a7 += b2f(u0.w >> 16)*w0;
    a0 += b2f(u1.x & 0xffffu)*w1; a1 += b2f(u1.x >> 16)*w1;
    a2 += b2f(u1.y & 0xffffu)*w1; a3 += b2f(u1.y >> 16)*w1;
    a4 += b2f(u1.z & 0xffffu)*w1; a5 += b2f(u1.z >> 16)*w1;
    a6 += b2f(u1.w & 0xffffu)*w1; a7 += b2f(u1.w >> 16)*w1;
    a0 += b2f(u2.x & 0xffffu)*w2; a1 += b2f(u2.x >> 16)*w2;
    a2 += b2f(u2.y & 0xffffu)*w2; a3 += b2f(u2.y >> 16)*w2;
    a4 += b2f(u2.z & 0xffffu)*w2; a5 += b2f(u2.z >> 16)*w2;
    a6 += b2f(u2.w & 0xffffu)*w2; a7 += b2f(u2.w >> 16)*w2;
    a0 += b2f(u3.x & 0xffffu)*w3; a1 += b2f(u3.x >> 16)*w3;
    a2 += b2f(u3.y & 0xffffu)*w3; a3 += b2f(u3.y >> 16)*w3;
    a4 += b2f(u3.z & 0xffffu)*w3; a5 += b2f(u3.z >> 16)*w3;
    a6 += b2f(u3.w & 0xffffu)*w3; a7 += b2f(u3.w >> 16)*w3;
  }
  for (; e < end; ++e){
    int s0 = col[e];
    uint4 u0 = ((const uint4*)(h + (size_t)s0*512))[lane];
    float w0 = __expf(lrelu02(asrc[s0*4 + hh] + adst_i));
    wsum += w0;
    a0 += b2f(u0.x & 0xffffu)*w0; a1 += b2f(u0.x >> 16)*w0;
    a2 += b2f(u0.y & 0xffffu)*w0; a3 += b2f(u0.y >> 16)*w0;
    a4 += b2f(u0.z & 0xffffu)*w0; a5 += b2f(u0.z >> 16)*w0;
    a6 += b2f(u0.w & 0xffffu)*w0; a7 += b2f(u0.w >> 16)*w0;
  }
  float inv = 1.f / fmaxf(wsum, 1e-16f);
  int ch = lane*8;
  float o0 = elu1(a0*inv + bias[ch+0]);
  float o1 = elu1(a1*inv + bias[ch+1]);
  float o2 = elu1(a2*inv + bias[ch+2]);
  float o3 = elu1(a3*inv + bias[ch+3]);
  float o4 = elu1(a4*inv + bias[ch+4]);
  float o5 = elu1(a5*inv + bias[ch+5]);
  float o6 = elu1(a6*inv + bias[ch+6]);
  float o7 = elu1(a7*inv + bias[ch+7]);
  ((uint4*)(outb + (size_t)n*512))[lane] =
      make_uint4(packbf(o0,o1), packbf(o2,o3), packbf(o4,o5), packbf(o6,o7));
}

// ---------------- layer-2 (H=1) aggregation, single pass, 8-deep prefetch ----------------
__global__ void agg1_kernel(const unsigned short* __restrict__ h,
                            const float* __restrict__ asrc,
                            const float* __restrict__ adst,
                            const float* __restrict__ bias,
                            const int* __restrict__ rp,
                            const int* __restrict__ col,
                            unsigned short* __restrict__ outb, int N){
  const int C = 128;
  int lane = threadIdx.x & 63;
  int n = blockIdx.x*4 + (threadIdx.x >> 6);
  if (n >= N) return;
  int beg = rp[n], end = rp[n+1];
  float adst_i = adst[n];
  float wself = __expf(lrelu02(asrc[n] + adst_i));
  const unsigned int* hp = (const unsigned int*)(h + (size_t)n*C);
  unsigned int us = hp[lane];
  float acc0 = b2f(us & 0xffffu)*wself, acc1 = b2f(us >> 16)*wself;
  float wsum = wself;

  int e = beg;
  for (; e + 8 <= end; e += 8){
    int r0 = col[e],   r1 = col[e+1], r2 = col[e+2], r3 = col[e+3];
    int r4 = col[e+4], r5 = col[e+5], r6 = col[e+6], r7 = col[e+7];
    unsigned int u0 = ((const unsigned int*)(h + (size_t)r0*C))[lane];
    unsigned int u1 = ((const unsigned int*)(h + (size_t)r1*C))[lane];
    unsigned int u2 = ((const unsigned int*)(h + (size_t)r2*C))[lane];
    unsigned int u3 = ((const unsigned int*)(h + (size_t)r3*C))[lane];
    unsigned int u4 = ((const unsigned int*)(h + (size_t)r4*C))[lane];
    unsigned int u5 = ((const unsigned int*)(h + (size_t)r5*C))[lane];
    unsigned int u6 = ((const unsigned int*)(h + (size_t)r6*C))[lane];
    unsigned int u7 = ((const unsigned int*)(h + (size_t)r7*C))[lane];
    float w0 = __expf(lrelu02(asrc[r0] + adst_i));
    float w1 = __expf(lrelu02(asrc[r1] + adst_i));
    float w2 = __expf(lrelu02(asrc[r2] + adst_i));
    float w3 = __expf(lrelu02(asrc[r3] + adst_i));
    float w4 = __expf(lrelu02(asrc[r4] + adst_i));
    float w5 = __expf(lrelu02(asrc[r5] + adst_i));
    float w6 = __expf(lrelu02(asrc[r6] + adst_i));
    float w7 = __expf(lrelu02(asrc[r7] + adst_i));
    wsum += w0 + w1 + w2 + w3 + w4 + w5 + w6 + w7;
    acc0 += b2f(u0 & 0xffffu)*w0; acc1 += b2f(u0 >> 16)*w0;
    acc0 += b2f(u1 & 0xffffu)*w1; acc1 += b2f(u1 >> 16)*w1;
    acc0 += b2f(u2 & 0xffffu)*w2; acc1 += b2f(u2 >> 16)*w2;
    acc0 += b2f(u3 & 0xffffu)*w3; acc1 += b2f(u3 >> 16)*w3;
    acc0 += b2f(u4 & 0xffffu)*w4; acc1 += b2f(u4 >> 16)*w4;
    acc0 += b2f(u5 & 0xffffu)*w5; acc1 += b2f(u5 >> 16)*w5;
    acc0 += b2f(u6 & 0xffffu)*w6; acc1 += b2f(u6 >> 16)*w6;
    acc0 += b2f(u7 & 0xffffu)*w7; acc1 += b2f(u7 >> 16)*w7;
  }
  for (; e + 4 <= end; e += 4){
    int r0 = col[e], r1 = col[e+1], r2 = col[e+2], r3 = col[e+3];
    unsigned int u0 = ((const unsigned int*)(h + (size_t)r0*C))[lane];
    unsigned int u1 = ((const unsigned int*)(h + (size_t)r1*C))[lane];
    unsigned int u2 = ((const unsigned int*)(h + (size_t)r2*C))[lane];
    unsigned int u3 = ((const unsigned int*)(h + (size_t)r3*C))[lane];
    float w0 = __expf(lrelu02(asrc[r0] + adst_i));
    float w1 = __expf(lrelu02(asrc[r1] + adst_i));
    float w2 = __expf(lrelu02(asrc[r2] + adst_i));
    float w3 = __expf(lrelu02(asrc[r3] + adst_i));
    wsum += w0 + w1 + w2 + w3;
    acc0 += b2f(u0 & 0xffffu)*w0; acc1 += b2f(u0 >> 16)*w0;
    acc0 += b2f(u1 & 0xffffu)*w1; acc1 += b2f(u1 >> 16)*w1;
    acc0 += b2f(u2 & 0xffffu)*w2; acc1 += b2f(u2 >> 16)*w2;
    acc0 += b2f(u3 & 0xffffu)*w3; acc1 += b2f(u3 >> 16)*w3;
  }
  for (; e < end; ++e){
    int r0 = col[e];
    unsigned int u0 = ((const unsigned int*)(h + (size_t)r0*C))[lane];
    float w0 = __expf(lrelu02(asrc[r0] + adst_i));
    wsum += w0;
    acc0 += b2f(u0 & 0xffffu)*w0; acc1 += b2f(u0 >> 16)*w0;
  }
  float inv = 1.f / fmaxf(wsum, 1e-16f);
  int c0 = 2*lane;
  float o0 = elu1(acc0*inv + bias[c0]);
  float o1 = elu1(acc1*inv + bias[c0+1]);
  ((unsigned int*)outb)[(size_t)n*(C/2) + lane] = packbf(o0, o1);
}

extern "C" void kernel_launch(void* const* d_in, const int* in_sizes, int n_in,
                              void* d_out, int out_size, void* d_ws, size_t ws_size,
                              hipStream_t stream){
  const float* x    = (const float*)d_in[0];
  const int*   ei   = (const int*)d_in[1];
  const int*   eli  = (const int*)d_in[3];
  const float* attr = (const float*)d_in[4];
  const float* W1   = (const float*)d_in[5];
  const float* as1  = (const float*)d_in[6];
  const float* ad1  = (const float*)d_in[7];
  const float* b1   = (const float*)d_in[8];
  const float* W2   = (const float*)d_in[9];
  const float* as2  = (const float*)d_in[10];
  const float* ad2  = (const float*)d_in[11];
  const float* b2   = (const float*)d_in[12];
  const float* mw1  = (const float*)d_in[13];
  const float* mb1  = (const float*)d_in[14];
  const float* mw2  = (const float*)d_in[15];
  const float* mb2  = (const float*)d_in[16];
  float* out = (float*)d_out;

  const int N  = in_sizes[0]/128;   // 10000
  const int E  = in_sizes[1]/2;     // 160000
  const int EL = in_sizes[3]/2;     // 100000
  const int H1 = 4, C = 128;
  const int K1 = 128, N1 = 512;
  const int K2 = 512, N2 = 128;

  // ---- workspace layout: live-small-buffers first, then phase-1 chain
  char* ws = (char*)d_ws;
  auto al = [](size_t x){ return (x + 255) & ~(size_t)255; };
  size_t off = 0;
  unsigned short* W1t  = (unsigned short*)(ws + off); off += al((size_t)N1*K1*2);
  unsigned short* W2t  = (unsigned short*)(ws + off); off += al((size_t)N2*K2*2);
  unsigned short* mw1t = (unsigned short*)(ws + off); off += al((size_t)64*160*2);
  float* asrc1 = (float*)(ws + off); off += al((size_t)N*H1*4);
  float* adst1 = (float*)(ws + off); off += al((size_t)N*H1*4);
  float* asrc2 = (float*)(ws + off); off += al((size_t)N*4);
  float* adst2 = (float*)(ws + off); off += al((size_t)N*4);
  int* cnt = (int*)(ws + off); off += (size_t)N*4;       // cnt+fl adjacent, zeroed by conv_all
  int* fl  = (int*)(ws + off); off += al((size_t)N*4);
  int* rp  = (int*)(ws + off); off += al((size_t)(N+1)*4);
  int* col = (int*)(ws + off); off += al((size_t)E*4);
  unsigned short* out2b = (unsigned short*)(ws + off); off += al((size_t)N*C*2);
  size_t A0 = off;
  unsigned short* xb    = (unsigned short*)(ws + A0);
  unsigned short* h1    = (unsigned short*)(ws + A0 + al((size_t)N*K1*2));
  unsigned short* out1b = (unsigned short*)((char*)h1 + al((size_t)N*N1*2));
  float*          part  = (float*)((char*)out1b + al((size_t)N*N1*2));
  unsigned short* h2b   = (unsigned short*)((char*)part + al((size_t)4*N*N2*4));

  // ---- fused conversions + cnt/fl zeroing ----
  const int NZ = 2*N;
  conv_all_kernel<<<(461312 + NZ + 255)/256, 256, 0, stream>>>(
      x, xb, W1, W1t, W2, W2t, mw1, mw1t, cnt, NZ);

  // ---- CSR build: one cooperative kernel (hist + scan + fill) ----
  {
    int E_ = E, N_ = N;
    const int* ei_ = ei;
    int* cnt_ = cnt; int* rp_ = rp; int* fl_ = fl; int* col_ = col;
    void* args[] = { (void*)&ei_, (void*)&cnt_, (void*)&rp_, (void*)&fl_,
                     (void*)&col_, (void*)&E_, (void*)&N_ };
    hipLaunchCooperativeKernel((void*)csr_kernel, dim3(512), dim3(256), args, 0, stream);
  }

  // ---- GAT layer 1 (BN=64) ----
  mgemm_kernel<64,1,0,0,1><<<dim3(N1/64, (N+127)/128, 1), 256, 0, stream>>>(
      xb, W1t, nullptr, h1, N, N1, K1);
  attn4_kernel<<<(N+3)/4, 256, 0, stream>>>(h1, as1, ad1, asrc1, adst1, N);
  agg4_kernel<<<(N+3)/4, 256, 0, stream>>>(h1, asrc1, adst1, b1, rp, col, out1b, N);

  // ---- GAT layer 2 (BN=64, splitK=4; attn fused into reduce) ----
  mgemm_kernel<64,4,0,0,0><<<dim3(N2/64, (N+127)/128, 4), 256, 0, stream>>>(
      out1b, W2t, nullptr, part, N, N2, K2);
  reduce4b_attn_kernel<<<(N*32+255)/256, 256, 0, stream>>>(
      (const float4*)part, (uint2*)h2b, as2, ad2, asrc2, adst2, N, N*N2/4);
  agg1_kernel<<<(N+3)/4, 256, 0, stream>>>(h2b, asrc2, adst2, b2, rp, col, out2b, N);

  // ---- edge MLP mega-kernel: feats-gather staging + GEMM + LDS final layer ----
  mgemm_mlp2_kernel<<<dim3(1, (EL+127)/128, 1), 256, 0, stream>>>(
      out2b, eli, attr, mw1t, mb1, mw2, mb2, out, EL);
}

// Round 15
// 124.475 us; speedup vs baseline: 1.9973x; 1.9973x over previous
//
#include <hip/hip_runtime.h>
#include <hip/hip_bf16.h>
#include <cstdint>

typedef __attribute__((ext_vector_type(8))) short bf16x8;
typedef __attribute__((ext_vector_type(4))) float f32x4;

__device__ __forceinline__ float lrelu02(float x){ return x > 0.f ? x : 0.2f*x; }
__device__ __forceinline__ float elu1(float x){ return x > 0.f ? x : __expf(x)-1.f; }
__device__ __forceinline__ unsigned short bf16_rne(float f){
  unsigned int u = __float_as_uint(f);
  u += 0x7FFFu + ((u >> 16) & 1u);
  return (unsigned short)(u >> 16);
}
__device__ __forceinline__ float b2f(unsigned int hi16){ return __uint_as_float(hi16 << 16); }
__device__ __forceinline__ unsigned int packbf(float a, float b){
  return (unsigned int)bf16_rne(a) | ((unsigned int)bf16_rne(b) << 16);
}

// ---------------- CSR build ----------------
__global__ void hist_kernel(const int* __restrict__ ei, int* __restrict__ cnt, int E){
  int e = blockIdx.x*blockDim.x + threadIdx.x;
  if (e < E) atomicAdd(&cnt[ei[E + e]], 1);
}

__global__ void scan_kernel(const int* __restrict__ cnt, int* __restrict__ rp, int N){
  __shared__ int part[1024];
  const int PER = 16;
  int t = threadIdx.x;
  int base = t*PER;
  int local[PER]; int s = 0;
  #pragma unroll
  for (int i=0;i<PER;i++){ int idx=base+i; int v = (idx<N)? cnt[idx] : 0; local[i]=s; s+=v; }
  part[t]=s; __syncthreads();
  for (int off=1; off<1024; off<<=1){
    int v = (t>=off)? part[t-off] : 0;
    __syncthreads();
    part[t] += v;
    __syncthreads();
  }
  int ex = (t>0)? part[t-1] : 0;
  #pragma unroll
  for (int i=0;i<PER;i++){ int idx=base+i; if (idx<N) rp[idx] = ex + local[i]; }
  if (t==0) rp[N] = part[1023];
}

__global__ void fill_kernel(const int* __restrict__ ei, const int* __restrict__ rp,
                            int* __restrict__ fl, int* __restrict__ col, int E){
  int e = blockIdx.x*blockDim.x + threadIdx.x;
  if (e >= E) return;
  int d = ei[E+e];
  int pos = rp[d] + atomicAdd(&fl[d], 1);
  col[pos] = ei[e];
}

// ---------------- fused conversions + cnt/fl zeroing ----------------
// ranges: [0,320000) f2b x (4-wide); [320000,385536) W1t; [385536,451072) W2t;
//         [451072,461312) mw1t; [461312,461312+nz) zero cnt+fl (2N ints, adjacent)
__global__ void conv_all_kernel(const float* __restrict__ x, unsigned short* __restrict__ xb,
                                const float* __restrict__ W1, unsigned short* __restrict__ W1t,
                                const float* __restrict__ W2, unsigned short* __restrict__ W2t,
                                const float* __restrict__ mw1, unsigned short* __restrict__ mw1t,
                                int* __restrict__ zbase, int nz){
  int t = blockIdx.x*256 + threadIdx.x;
  if (t < 320000){
    int i = t*4;
    float4 v = *(const float4*)(x + i);
    xb[i+0] = bf16_rne(v.x); xb[i+1] = bf16_rne(v.y);
    xb[i+2] = bf16_rne(v.z); xb[i+3] = bf16_rne(v.w);
  } else if (t < 385536){
    int i = t - 320000;                 // W1 [128][512] -> W1t [512][128]
    int n = i >> 7, k = i & 127;
    W1t[i] = bf16_rne(W1[(size_t)k*512 + n]);
  } else if (t < 451072){
    int i = t - 385536;                 // W2 [512][128] -> W2t [128][512]
    int n = i >> 9, k = i & 511;
    W2t[i] = bf16_rne(W2[(size_t)k*128 + n]);
  } else if (t < 461312){
    int i = t - 451072;                 // mw1 [144][64] -> mw1t [64][160] (pad)
    int n = i / 160, k = i % 160;
    mw1t[i] = (k < 144) ? bf16_rne(mw1[(size_t)k*64 + n]) : (unsigned short)0;
  } else if (t < 461312 + nz){
    zbase[t - 461312] = 0;
  }
}

// ---------------- MFMA bf16 GEMM: C = A[M,K] @ Bt[N,K]^T ----------
// OUTB=1: write bf16 (SPLITK must be 1). OUTB=0: write f32 (+z-sliced for SPLITK).
template<int BN, int SPLITK, int RELU, int WB, int OUTB>
__global__ __launch_bounds__(256) void mgemm_kernel(
    const unsigned short* __restrict__ A,  // [M][K] bf16
    const unsigned short* __restrict__ Bt, // [N][K] bf16
    const float* __restrict__ bias,
    void* __restrict__ C,
    int M, int N, int K){
  const int BM = 128, BK = 32, LDP = BK + 8;
  const int NF = BN/32;
  __shared__ unsigned short As[BM*LDP];
  __shared__ unsigned short Bs[BN*LDP];
  int tid = threadIdx.x;
  int lane = tid & 63, wid = tid >> 6;
  int wr = wid >> 1, wc = wid & 1;
  int row0 = blockIdx.y*BM, col0 = blockIdx.x*BN;
  int kchunk = K / SPLITK;
  int k0base = blockIdx.z * kchunk;
  f32x4 acc[4][NF];
  #pragma unroll
  for (int m=0;m<4;m++)
    #pragma unroll
    for (int n=0;n<NF;n++) acc[m][n] = (f32x4){0.f,0.f,0.f,0.f};

  for (int kt = 0; kt < kchunk; kt += BK){
    int k0 = k0base + kt;
    #pragma unroll
    for (int i=0;i<(BM*4)/256;i++){
      int li = i*256 + tid;
      int r = li >> 2, q = li & 3;
      int gr = row0 + r;
      uint4 v = make_uint4(0u,0u,0u,0u);
      if (gr < M) v = *(const uint4*)(A + (size_t)gr*K + k0 + q*8);
      *(uint4*)(&As[r*LDP + q*8]) = v;
    }
    #pragma unroll
    for (int i=0;i<(BN*4)/256;i++){
      int li = i*256 + tid;
      int r = li >> 2, q = li & 3;
      int gn = col0 + r;
      uint4 v = make_uint4(0u,0u,0u,0u);
      if (gn < N) v = *(const uint4*)(Bt + (size_t)gn*K + k0 + q*8);
      *(uint4*)(&Bs[r*LDP + q*8]) = v;
    }
    __syncthreads();
    int kq = (lane >> 4) * 8;
    bf16x8 af[4], bfr[NF];
    #pragma unroll
    for (int m=0;m<4;m++)
      af[m] = *(const bf16x8*)(&As[(wr*64 + m*16 + (lane&15))*LDP + kq]);
    #pragma unroll
    for (int n=0;n<NF;n++)
      bfr[n] = *(const bf16x8*)(&Bs[(wc*(BN/2) + n*16 + (lane&15))*LDP + kq]);
    #pragma unroll
    for (int m=0;m<4;m++)
      #pragma unroll
      for (int n=0;n<NF;n++)
        acc[m][n] = __builtin_amdgcn_mfma_f32_16x16x32_bf16(af[m], bfr[n], acc[m][n], 0, 0, 0);
    __syncthreads();
  }
  #pragma unroll
  for (int m=0;m<4;m++){
    #pragma unroll
    for (int j=0;j<4;j++){
      int r = row0 + wr*64 + m*16 + (lane>>4)*4 + j;
      if (r >= M) continue;
      #pragma unroll
      for (int n=0;n<NF;n++){
        int c = col0 + wc*(BN/2) + n*16 + (lane&15);
        float v = acc[m][n][j];
        if (WB) v += bias[c];
        if (RELU) v = fmaxf(v, 0.f);
        if (OUTB){
          ((unsigned short*)C)[(size_t)r*N + c] = bf16_rne(v);
        } else {
          float* Cb = (float*)C + (size_t)blockIdx.z * M * N;
          Cb[(size_t)r*N + c] = v;
        }
      }
    }
  }
}

// ---------------- edge-MLP mega-kernel: feats-gather staging + GEMM + LDS-tile final layer
__global__ __launch_bounds__(256) void mgemm_mlp2_kernel(
    const unsigned short* __restrict__ hf,   // out2b [N][128] bf16
    const int* __restrict__ eli,             // [2][M]
    const float* __restrict__ attr,          // [M][16]
    const unsigned short* __restrict__ Bt,   // mw1t [64][160] bf16
    const float* __restrict__ mb1,
    const float* __restrict__ w2,            // [64][2]
    const float* __restrict__ b2,            // [2]
    float* __restrict__ out, int M){
  const int BK = 32, LDP = BK + 8, K = 160;
  __shared__ unsigned short As[128*LDP];
  __shared__ unsigned short Bs[64*LDP];
  __shared__ float hid[128][65];
  __shared__ float w2s[128];
  int tid = threadIdx.x;
  int lane = tid & 63, wid = tid >> 6;
  int wr = wid >> 1, wc = wid & 1;
  int row0 = blockIdx.y*128;
  if (tid < 128) w2s[tid] = w2[tid];

  int r0_ = tid >> 2, q_ = tid & 3;
  int r1_ = 64 + r0_;
  int gr0 = row0 + r0_, gr1 = row0 + r1_;
  bool ok0 = gr0 < M, ok1 = gr1 < M;
  int s0=0, d0=0, s1=0, d1=0;
  if (ok0){ s0 = eli[gr0]; d0 = eli[M + gr0]; }
  if (ok1){ s1 = eli[gr1]; d1 = eli[M + gr1]; }

  auto make_chunk = [&](int s, int d, int gr, bool ok, int k) -> uint4 {
    uint4 v = make_uint4(0u,0u,0u,0u);
    if (!ok) return v;
    if (k < 128){
      uint4 a = *(const uint4*)(hf + (size_t)s*128 + k);
      uint4 b = *(const uint4*)(hf + (size_t)d*128 + k);
      v.x = packbf(b2f(a.x & 0xffffu)*b2f(b.x & 0xffffu), b2f(a.x >> 16)*b2f(b.x >> 16));
      v.y = packbf(b2f(a.y & 0xffffu)*b2f(b.y & 0xffffu), b2f(a.y >> 16)*b2f(b.y >> 16));
      v.z = packbf(b2f(a.z & 0xffffu)*b2f(b.z & 0xffffu), b2f(a.z >> 16)*b2f(b.z >> 16));
      v.w = packbf(b2f(a.w & 0xffffu)*b2f(b.w & 0xffffu), b2f(a.w >> 16)*b2f(b.w >> 16));
    } else if (k < 144){
      const float* pa = attr + (size_t)gr*16 + (k - 128);
      float4 x0 = *(const float4*)pa;
      float4 x1 = *(const float4*)(pa + 4);
      v.x = packbf(x0.x, x0.y); v.y = packbf(x0.z, x0.w);
      v.z = packbf(x1.x, x1.y); v.w = packbf(x1.z, x1.w);
    }
    return v;
  };

  f32x4 acc[4][2];
  #pragma unroll
  for (int m=0;m<4;m++){ acc[m][0] = (f32x4){0,0,0,0}; acc[m][1] = (f32x4){0,0,0,0}; }

  for (int k0 = 0; k0 < K; k0 += BK){
    int k = k0 + q_*8;
    *(uint4*)(&As[r0_*LDP + q_*8]) = make_chunk(s0, d0, gr0, ok0, k);
    *(uint4*)(&As[r1_*LDP + q_*8]) = make_chunk(s1, d1, gr1, ok1, k);
    {
      int r = tid >> 2, q = tid & 3;
      uint4 v = *(const uint4*)(Bt + (size_t)r*K + k0 + q*8);
      *(uint4*)(&Bs[r*LDP + q*8]) = v;
    }
    __syncthreads();
    int kq = (lane >> 4) * 8;
    bf16x8 af[4], bfr[2];
    #pragma unroll
    for (int m=0;m<4;m++)
      af[m] = *(const bf16x8*)(&As[(wr*64 + m*16 + (lane&15))*LDP + kq]);
    #pragma unroll
    for (int n=0;n<2;n++)
      bfr[n] = *(const bf16x8*)(&Bs[(wc*32 + n*16 + (lane&15))*LDP + kq]);
    #pragma unroll
    for (int m=0;m<4;m++)
      #pragma unroll
      for (int n=0;n<2;n++)
        acc[m][n] = __builtin_amdgcn_mfma_f32_16x16x32_bf16(af[m], bfr[n], acc[m][n], 0, 0, 0);
    __syncthreads();
  }
  // phase 2a: stage relu(acc + mb1) into LDS with the proven (r,c) mapping
  #pragma unroll
  for (int m=0;m<4;m++){
    #pragma unroll
    for (int j=0;j<4;j++){
      int r = wr*64 + m*16 + (lane>>4)*4 + j;
      #pragma unroll
      for (int n=0;n<2;n++){
        int c = wc*32 + n*16 + (lane&15);
        hid[r][c] = fmaxf(acc[m][n][j] + mb1[c], 0.f);
      }
    }
  }
  __syncthreads();
  // phase 2b: per-row dot with w2; thread t owns row t>>1, half t&1
  int r = tid >> 1, hf2 = tid & 1;
  int cbase = hf2*32;
  float p0 = 0.f, p1 = 0.f;
  #pragma unroll
  for (int c=0;c<32;c++){
    float v = hid[r][cbase + c];
    p0 += v * w2s[(cbase + c)*2 + 0];
    p1 += v * w2s[(cbase + c)*2 + 1];
  }
  p0 += __shfl_xor(p0, 1, 64);
  p1 += __shfl_xor(p1, 1, 64);
  if (hf2 == 0 && row0 + r < M){
    out[(size_t)(row0 + r)*2 + 0] = p0 + b2[0];
    out[(size_t)(row0 + r)*2 + 1] = p1 + b2[1];
  }
}

// sum 4 split-K partials -> bf16, fused layer-2 attention coefficients.
__global__ void reduce4b_attn_kernel(const float4* __restrict__ p, uint2* __restrict__ o,
                                     const float* __restrict__ as2, const float* __restrict__ ad2,
                                     float* __restrict__ asrc, float* __restrict__ adst,
                                     int N, int s4){
  int idx = blockIdx.x*256 + threadIdx.x;
  int n = idx >> 5;
  if (n >= N) return;
  float4 a = p[idx], b = p[idx+s4], c = p[idx+2*s4], d = p[idx+3*s4];
  float rx = a.x+b.x+c.x+d.x, ry = a.y+b.y+c.y+d.y;
  float rz = a.z+b.z+c.z+d.z, rw = a.w+b.w+c.w+d.w;
  o[idx] = make_uint2(packbf(rx, ry), packbf(rz, rw));
  int c4 = (idx & 31)*4;
  float ps = rx*as2[c4] + ry*as2[c4+1] + rz*as2[c4+2] + rw*as2[c4+3];
  float pd = rx*ad2[c4] + ry*ad2[c4+1] + rz*ad2[c4+2] + rw*ad2[c4+3];
  #pragma unroll
  for (int off=1; off<32; off<<=1){ ps += __shfl_xor(ps,off,64); pd += __shfl_xor(pd,off,64); }
  if ((idx & 31) == 0){ asrc[n] = ps; adst[n] = pd; }
}

// ---------------- layer-1 attention coefficients, head-merged: one wave per node
__global__ void attn4_kernel(const unsigned short* __restrict__ h,
                             const float* __restrict__ att_src,   // [512]
                             const float* __restrict__ att_dst,
                             float* __restrict__ asrc, float* __restrict__ adst, int N){
  int lane = threadIdx.x & 63;
  int n = blockIdx.x*4 + (threadIdx.x >> 6);
  if (n >= N) return;
  const uint4* hp = (const uint4*)(h + (size_t)n*512);
  uint4 u = hp[lane];
  int ch = lane*8;
  float f0 = b2f(u.x & 0xffffu), f1 = b2f(u.x >> 16);
  float f2 = b2f(u.y & 0xffffu), f3 = b2f(u.y >> 16);
  float f4 = b2f(u.z & 0xffffu), f5 = b2f(u.z >> 16);
  float f6 = b2f(u.w & 0xffffu), f7 = b2f(u.w >> 16);
  float s = f0*att_src[ch+0] + f1*att_src[ch+1] + f2*att_src[ch+2] + f3*att_src[ch+3]
          + f4*att_src[ch+4] + f5*att_src[ch+5] + f6*att_src[ch+6] + f7*att_src[ch+7];
  float d = f0*att_dst[ch+0] + f1*att_dst[ch+1] + f2*att_dst[ch+2] + f3*att_dst[ch+3]
          + f4*att_dst[ch+4] + f5*att_dst[ch+5] + f6*att_dst[ch+6] + f7*att_dst[ch+7];
  #pragma unroll
  for (int o=1; o<16; o<<=1){ s += __shfl_xor(s, o, 64); d += __shfl_xor(d, o, 64); }
  if ((lane & 15) == 0){
    int hh = lane >> 4;
    asrc[n*4 + hh] = s; adst[n*4 + hh] = d;
  }
}

// ---------------- layer-1 aggregation, head-merged single pass, 8-deep prefetch
__global__ void agg4_kernel(const unsigned short* __restrict__ h,   // [N][512]
                            const float* __restrict__ asrc,         // [N][4]
                            const float* __restrict__ adst,
                            const float* __restrict__ bias,         // [512]
                            const int* __restrict__ rp,
                            const int* __restrict__ col,
                            unsigned short* __restrict__ outb, int N){
  int lane = threadIdx.x & 63;
  int n = blockIdx.x*4 + (threadIdx.x >> 6);
  if (n >= N) return;
  int hh = lane >> 4;
  int beg = rp[n], end = rp[n+1];
  float adst_i = adst[n*4 + hh];
  float wself = __expf(lrelu02(asrc[n*4 + hh] + adst_i));
  const uint4* hp = (const uint4*)(h + (size_t)n*512);
  uint4 us = hp[lane];
  float a0 = b2f(us.x & 0xffffu)*wself, a1 = b2f(us.x >> 16)*wself;
  float a2 = b2f(us.y & 0xffffu)*wself, a3 = b2f(us.y >> 16)*wself;
  float a4 = b2f(us.z & 0xffffu)*wself, a5 = b2f(us.z >> 16)*wself;
  float a6 = b2f(us.w & 0xffffu)*wself, a7 = b2f(us.w >> 16)*wself;
  float wsum = wself;

  int e = beg;
  for (; e + 8 <= end; e += 8){
    int s0 = col[e],   s1 = col[e+1], s2 = col[e+2], s3 = col[e+3];
    int s4 = col[e+4], s5 = col[e+5], s6 = col[e+6], s7 = col[e+7];
    uint4 u0 = ((const uint4*)(h + (size_t)s0*512))[lane];
    uint4 u1 = ((const uint4*)(h + (size_t)s1*512))[lane];
    uint4 u2 = ((const uint4*)(h + (size_t)s2*512))[lane];
    uint4 u3 = ((const uint4*)(h + (size_t)s3*512))[lane];
    uint4 u4 = ((const uint4*)(h + (size_t)s4*512))[lane];
    uint4 u5 = ((const uint4*)(h + (size_t)s5*512))[lane];
    uint4 u6 = ((const uint4*)(h + (size_t)s6*512))[lane];
    uint4 u7 = ((const uint4*)(h + (size_t)s7*512))[lane];
    float w0 = __expf(lrelu02(asrc[s0*4 + hh] + adst_i));
    float w1 = __expf(lrelu02(asrc[s1*4 + hh] + adst_i));
    float w2 = __expf(lrelu02(asrc[s2*4 + hh] + adst_i));
    float w3 = __expf(lrelu02(asrc[s3*4 + hh] + adst_i));
    float w4 = __expf(lrelu02(asrc[s4*4 + hh] + adst_i));
    float w5 = __expf(lrelu02(asrc[s5*4 + hh] + adst_i));
    float w6 = __expf(lrelu02(asrc[s6*4 + hh] + adst_i));
    float w7 = __expf(lrelu02(asrc[s7*4 + hh] + adst_i));
    wsum += w0 + w1 + w2 + w3 + w4 + w5 + w6 + w7;
    a0 += b2f(u0.x & 0xffffu)*w0; a1 += b2f(u0.x >> 16)*w0;
    a2 += b2f(u0.y & 0xffffu)*w0; a3 += b2f(u0.y >> 16)*w0;
    a4 += b2f(u0.z & 0xffffu)*w0; a5 += b2f(u0.z >> 16)*w0;
    a6 += b2f(u0.w & 0xffffu)*w0; a7 += b2f(u0.w >> 16)*w0;
    a0 += b2f(u1.x & 0xffffu)*w1; a1 += b2f(u1.x >> 16)*w1;
    a2 += b2f(u1.y & 0xffffu)*w1; a3 += b2f(u1.y >> 16)*w1;
    a4 += b2f(u1.z & 0xffffu)*w1; a5 += b2f(u1.z >> 16)*w1;
    a6 += b2f(u1.w & 0xffffu)*w1; a7 += b2f(u1.w >> 16)*w1;
    a0 += b2f(u2.x & 0xffffu)*w2; a1 += b2f(u2.x >> 16)*w2;
    a2 += b2f(u2.y & 0xffffu)*w2; a3 += b2f(u2.y >> 16)*w2;
    a4 += b2f(u2.z & 0xffffu)*w2; a5 += b2f(u2.z >> 16)*w2;
    a6 += b2f(u2.w & 0xffffu)*w2; a7 += b2f(u2.w >> 16)*w2;
    a0 += b2f(u3.x & 0xffffu)*w3; a1 += b2f(u3.x >> 16)*w3;
    a2 += b2f(u3.y & 0xffffu)*w3; a3 += b2f(u3.y >> 16)*w3;
    a4 += b2f(u3.z & 0xffffu)*w3; a5 += b2f(u3.z >> 16)*w3;
    a6 += b2f(u3.w & 0xffffu)*w3; a7 += b2f(u3.w >> 16)*w3;
    a0 += b2f(u4.x & 0xffffu)*w4; a1 += b2f(u4.x >> 16)*w4;
    a2 += b2f(u4.y & 0xffffu)*w4; a3 += b2f(u4.y >> 16)*w4;
    a4 += b2f(u4.z & 0xffffu)*w4; a5 += b2f(u4.z >> 16)*w4;
    a6 += b2f(u4.w & 0xffffu)*w4; a7 += b2f(u4.w >> 16)*w4;
    a0 += b2f(u5.x & 0xffffu)*w5; a1 += b2f(u5.x >> 16)*w5;
    a2 += b2f(u5.y & 0xffffu)*w5; a3 += b2f(u5.y >> 16)*w5;
    a4 += b2f(u5.z & 0xffffu)*w5; a5 += b2f(u5.z >> 16)*w5;
    a6 += b2f(u5.w & 0xffffu)*w5; a7 += b2f(u5.w >> 16)*w5;
    a0 += b2f(u6.x & 0xffffu)*w6; a1 += b2f(u6.x >> 16)*w6;
    a2 += b2f(u6.y & 0xffffu)*w6; a3 += b2f(u6.y >> 16)*w6;
    a4 += b2f(u6.z & 0xffffu)*w6; a5 += b2f(u6.z >> 16)*w6;
    a6 += b2f(u6.w & 0xffffu)*w6; a7 += b2f(u6.w >> 16)*w6;
    a0 += b2f(u7.x & 0xffffu)*w7; a1 += b2f(u7.x >> 16)*w7;
    a2 += b2f(u7.y & 0xffffu)*w7; a3 += b2f(u7.y >> 16)*w7;
    a4 += b2f(u7.z & 0xffffu)*w7; a5 += b2f(u7.z >> 16)*w7;
    a6 += b2f(u7.w & 0xffffu)*w7; a7 += b2f(u7.w >> 16)*w7;
  }
  for (; e + 4 <= end; e += 4){
    int s0 = col[e], s1 = col[e+1], s2 = col[e+2], s3 = col[e+3];
    uint4 u0 = ((const uint4*)(h + (size_t)s0*512))[lane];
    uint4 u1 = ((const uint4*)(h + (size_t)s1*512))[lane];
    uint4 u2 = ((const uint4*)(h + (size_t)s2*512))[lane];
    uint4 u3 = ((const uint4*)(h + (size_t)s3*512))[lane];
    float w0 = __expf(lrelu02(asrc[s0*4 + hh] + adst_i));
    float w1 = __expf(lrelu02(asrc[s1*4 + hh] + adst_i));
    float w2 = __expf(lrelu02(asrc[s2*4 + hh] + adst_i));
    float w3 = __expf(lrelu02(asrc[s3*4 + hh] + adst_i));
    wsum += w0 + w1 + w2 + w3;
    a0 += b2f(u0.x & 0xffffu)*w0; a1 += b2f(u0.x >> 16)*w0;
    a2 += b2f(u0.y & 0xffffu)*w0; a3 += b2f(u0.y >> 16)*w0;
    a4 += b2f(u0.z & 0xffffu)*w0; a5 += b2f(u0.z >> 16)*w0;
    a6 += b2f(u0.w & 0xffffu)*w0; a7 += b2f(u0.w >> 16)*w0;
    a0 += b2f(u1.x & 0xffffu)*w1; a1 += b2f(u1.x >> 16)*w1;
    a2 += b2f(u1.y & 0xffffu)*w1; a3 += b2f(u1.y >> 16)*w1;
    a4 += b2f(u1.z & 0xffffu)*w1; a5 += b2f(u1.z >> 16)*w1;
    a6 += b2f(u1.w & 0xffffu)*w1; a7 += b2f(u1.w >> 16)*w1;
    a0 += b2f(u2.x & 0xffffu)*w2; a1 += b2f(u2.x >> 16)*w2;
    a2 += b2f(u2.y & 0xffffu)*w2; a3 += b2f(u2.y >> 16)*w2;
    a4 += b2f(u2.z & 0xffffu)*w2; a5 += b2f(u2.z >> 16)*w2;
    a6 += b2f(u2.w & 0xffffu)*w2; a7 += b2f(u2.w >> 16)*w2;
    a0 += b2f(u3.x & 0xffffu)*w3; a1 += b2f(u3.x >> 16)*w3;
    a2 += b2f(u3.y & 0xffffu)*w3; a3 += b2f(u3.y >> 16)*w3;
    a4 += b2f(u3.z & 0xffffu)*w3; a5 += b2f(u3.z >> 16)*w3;
    a6 += b2f(u3.w & 0xffffu)*w3; a7 += b2f(u3.w >> 16)*w3;
  }
  for (; e < end; ++e){
    int s0 = col[e];
    uint4 u0 = ((const uint4*)(h + (size_t)s0*512))[lane];
    float w0 = __expf(lrelu02(asrc[s0*4 + hh] + adst_i));
    wsum += w0;
    a0 += b2f(u0.x & 0xffffu)*w0; a1 += b2f(u0.x >> 16)*w0;
    a2 += b2f(u0.y & 0xffffu)*w0; a3 += b2f(u0.y >> 16)*w0;
    a4 += b2f(u0.z & 0xffffu)*w0; a5 += b2f(u0.z >> 16)*w0;
    a6 += b2f(u0.w & 0xffffu)*w0; a7 += b2f(u0.w >> 16)*w0;
  }
  float inv = 1.f / fmaxf(wsum, 1e-16f);
  int ch = lane*8;
  float o0 = elu1(a0*inv + bias[ch+0]);
  float o1 = elu1(a1*inv + bias[ch+1]);
  float o2 = elu1(a2*inv + bias[ch+2]);
  float o3 = elu1(a3*inv + bias[ch+3]);
  float o4 = elu1(a4*inv + bias[ch+4]);
  float o5 = elu1(a5*inv + bias[ch+5]);
  float o6 = elu1(a6*inv + bias[ch+6]);
  float o7 = elu1(a7*inv + bias[ch+7]);
  ((uint4*)(outb + (size_t)n*512))[lane] =
      make_uint4(packbf(o0,o1), packbf(o2,o3), packbf(o4,o5), packbf(o6,o7));
}

// ---------------- layer-2 (H=1) aggregation, single pass, 8-deep prefetch ----------------
__global__ void agg1_kernel(const unsigned short* __restrict__ h,
                            const float* __restrict__ asrc,
                            const float* __restrict__ adst,
                            const float* __restrict__ bias,
                            const int* __restrict__ rp,
                            const int* __restrict__ col,
                            unsigned short* __restrict__ outb, int N){
  const int C = 128;
  int lane = threadIdx.x & 63;
  int n = blockIdx.x*4 + (threadIdx.x >> 6);
  if (n >= N) return;
  int beg = rp[n], end = rp[n+1];
  float adst_i = adst[n];
  float wself = __expf(lrelu02(asrc[n] + adst_i));
  const unsigned int* hp = (const unsigned int*)(h + (size_t)n*C);
  unsigned int us = hp[lane];
  float acc0 = b2f(us & 0xffffu)*wself, acc1 = b2f(us >> 16)*wself;
  float wsum = wself;

  int e = beg;
  for (; e + 8 <= end; e += 8){
    int r0 = col[e],   r1 = col[e+1], r2 = col[e+2], r3 = col[e+3];
    int r4 = col[e+4], r5 = col[e+5], r6 = col[e+6], r7 = col[e+7];
    unsigned int u0 = ((const unsigned int*)(h + (size_t)r0*C))[lane];
    unsigned int u1 = ((const unsigned int*)(h + (size_t)r1*C))[lane];
    unsigned int u2 = ((const unsigned int*)(h + (size_t)r2*C))[lane];
    unsigned int u3 = ((const unsigned int*)(h + (size_t)r3*C))[lane];
    unsigned int u4 = ((const unsigned int*)(h + (size_t)r4*C))[lane];
    unsigned int u5 = ((const unsigned int*)(h + (size_t)r5*C))[lane];
    unsigned int u6 = ((const unsigned int*)(h + (size_t)r6*C))[lane];
    unsigned int u7 = ((const unsigned int*)(h + (size_t)r7*C))[lane];
    float w0 = __expf(lrelu02(asrc[r0] + adst_i));
    float w1 = __expf(lrelu02(asrc[r1] + adst_i));
    float w2 = __expf(lrelu02(asrc[r2] + adst_i));
    float w3 = __expf(lrelu02(asrc[r3] + adst_i));
    float w4 = __expf(lrelu02(asrc[r4] + adst_i));
    float w5 = __expf(lrelu02(asrc[r5] + adst_i));
    float w6 = __expf(lrelu02(asrc[r6] + adst_i));
    float w7 = __expf(lrelu02(asrc[r7] + adst_i));
    wsum += w0 + w1 + w2 + w3 + w4 + w5 + w6 + w7;
    acc0 += b2f(u0 & 0xffffu)*w0; acc1 += b2f(u0 >> 16)*w0;
    acc0 += b2f(u1 & 0xffffu)*w1; acc1 += b2f(u1 >> 16)*w1;
    acc0 += b2f(u2 & 0xffffu)*w2; acc1 += b2f(u2 >> 16)*w2;
    acc0 += b2f(u3 & 0xffffu)*w3; acc1 += b2f(u3 >> 16)*w3;
    acc0 += b2f(u4 & 0xffffu)*w4; acc1 += b2f(u4 >> 16)*w4;
    acc0 += b2f(u5 & 0xffffu)*w5; acc1 += b2f(u5 >> 16)*w5;
    acc0 += b2f(u6 & 0xffffu)*w6; acc1 += b2f(u6 >> 16)*w6;
    acc0 += b2f(u7 & 0xffffu)*w7; acc1 += b2f(u7 >> 16)*w7;
  }
  for (; e + 4 <= end; e += 4){
    int r0 = col[e], r1 = col[e+1], r2 = col[e+2], r3 = col[e+3];
    unsigned int u0 = ((const unsigned int*)(h + (size_t)r0*C))[lane];
    unsigned int u1 = ((const unsigned int*)(h + (size_t)r1*C))[lane];
    unsigned int u2 = ((const unsigned int*)(h + (size_t)r2*C))[lane];
    unsigned int u3 = ((const unsigned int*)(h + (size_t)r3*C))[lane];
    float w0 = __expf(lrelu02(asrc[r0] + adst_i));
    float w1 = __expf(lrelu02(asrc[r1] + adst_i));
    float w2 = __expf(lrelu02(asrc[r2] + adst_i));
    float w3 = __expf(lrelu02(asrc[r3] + adst_i));
    wsum += w0 + w1 + w2 + w3;
    acc0 += b2f(u0 & 0xffffu)*w0; acc1 += b2f(u0 >> 16)*w0;
    acc0 += b2f(u1 & 0xffffu)*w1; acc1 += b2f(u1 >> 16)*w1;
    acc0 += b2f(u2 & 0xffffu)*w2; acc1 += b2f(u2 >> 16)*w2;
    acc0 += b2f(u3 & 0xffffu)*w3; acc1 += b2f(u3 >> 16)*w3;
  }
  for (; e < end; ++e){
    int r0 = col[e];
    unsigned int u0 = ((const unsigned int*)(h + (size_t)r0*C))[lane];
    float w0 = __expf(lrelu02(asrc[r0] + adst_i));
    wsum += w0;
    acc0 += b2f(u0 & 0xffffu)*w0; acc1 += b2f(u0 >> 16)*w0;
  }
  float inv = 1.f / fmaxf(wsum, 1e-16f);
  int c0 = 2*lane;
  float o0 = elu1(acc0*inv + bias[c0]);
  float o1 = elu1(acc1*inv + bias[c0+1]);
  ((unsigned int*)outb)[(size_t)n*(C/2) + lane] = packbf(o0, o1);
}

extern "C" void kernel_launch(void* const* d_in, const int* in_sizes, int n_in,
                              void* d_out, int out_size, void* d_ws, size_t ws_size,
                              hipStream_t stream){
  const float* x    = (const float*)d_in[0];
  const int*   ei   = (const int*)d_in[1];
  const int*   eli  = (const int*)d_in[3];
  const float* attr = (const float*)d_in[4];
  const float* W1   = (const float*)d_in[5];
  const float* as1  = (const float*)d_in[6];
  const float* ad1  = (const float*)d_in[7];
  const float* b1   = (const float*)d_in[8];
  const float* W2   = (const float*)d_in[9];
  const float* as2  = (const float*)d_in[10];
  const float* ad2  = (const float*)d_in[11];
  const float* b2   = (const float*)d_in[12];
  const float* mw1  = (const float*)d_in[13];
  const float* mb1  = (const float*)d_in[14];
  const float* mw2  = (const float*)d_in[15];
  const float* mb2  = (const float*)d_in[16];
  float* out = (float*)d_out;

  const int N  = in_sizes[0]/128;   // 10000
  const int E  = in_sizes[1]/2;     // 160000
  const int EL = in_sizes[3]/2;     // 100000
  const int H1 = 4, C = 128;
  const int K1 = 128, N1 = 512;
  const int K2 = 512, N2 = 128;

  // ---- workspace layout: live-small-buffers first, then phase-1 chain
  char* ws = (char*)d_ws;
  auto al = [](size_t x){ return (x + 255) & ~(size_t)255; };
  size_t off = 0;
  unsigned short* W1t  = (unsigned short*)(ws + off); off += al((size_t)N1*K1*2);
  unsigned short* W2t  = (unsigned short*)(ws + off); off += al((size_t)N2*K2*2);
  unsigned short* mw1t = (unsigned short*)(ws + off); off += al((size_t)64*160*2);
  float* asrc1 = (float*)(ws + off); off += al((size_t)N*H1*4);
  float* adst1 = (float*)(ws + off); off += al((size_t)N*H1*4);
  float* asrc2 = (float*)(ws + off); off += al((size_t)N*4);
  float* adst2 = (float*)(ws + off); off += al((size_t)N*4);
  int* cnt = (int*)(ws + off); off += (size_t)N*4;       // cnt+fl adjacent, zeroed by conv_all
  int* fl  = (int*)(ws + off); off += al((size_t)N*4);
  int* rp  = (int*)(ws + off); off += al((size_t)(N+1)*4);
  int* col = (int*)(ws + off); off += al((size_t)E*4);
  unsigned short* out2b = (unsigned short*)(ws + off); off += al((size_t)N*C*2);
  size_t A0 = off;
  unsigned short* xb    = (unsigned short*)(ws + A0);
  unsigned short* h1    = (unsigned short*)(ws + A0 + al((size_t)N*K1*2));
  unsigned short* out1b = (unsigned short*)((char*)h1 + al((size_t)N*N1*2));
  float*          part  = (float*)((char*)out1b + al((size_t)N*N1*2));
  unsigned short* h2b   = (unsigned short*)((char*)part + al((size_t)4*N*N2*4));

  // ---- fused conversions + cnt/fl zeroing (replaces memset dispatch) ----
  const int NZ = 2*N;   // cnt + fl ints
  conv_all_kernel<<<(461312 + NZ + 255)/256, 256, 0, stream>>>(
      x, xb, W1, W1t, W2, W2t, mw1, mw1t, cnt, NZ);

  // ---- CSR build ----
  hist_kernel<<<(E+255)/256, 256, 0, stream>>>(ei, cnt, E);
  scan_kernel<<<1, 1024, 0, stream>>>(cnt, rp, N);
  fill_kernel<<<(E+255)/256, 256, 0, stream>>>(ei, rp, fl, col, E);

  // ---- GAT layer 1 (BN=64) ----
  mgemm_kernel<64,1,0,0,1><<<dim3(N1/64, (N+127)/128, 1), 256, 0, stream>>>(
      xb, W1t, nullptr, h1, N, N1, K1);
  attn4_kernel<<<(N+3)/4, 256, 0, stream>>>(h1, as1, ad1, asrc1, adst1, N);
  agg4_kernel<<<(N+3)/4, 256, 0, stream>>>(h1, asrc1, adst1, b1, rp, col, out1b, N);

  // ---- GAT layer 2 (BN=64, splitK=4; attn fused into reduce) ----
  mgemm_kernel<64,4,0,0,0><<<dim3(N2/64, (N+127)/128, 4), 256, 0, stream>>>(
      out1b, W2t, nullptr, part, N, N2, K2);
  reduce4b_attn_kernel<<<(N*32+255)/256, 256, 0, stream>>>(
      (const float4*)part, (uint2*)h2b, as2, ad2, asrc2, adst2, N, N*N2/4);
  agg1_kernel<<<(N+3)/4, 256, 0, stream>>>(h2b, asrc2, adst2, b2, rp, col, out2b, N);

  // ---- edge MLP mega-kernel: feats-gather staging + GEMM + LDS final layer ----
  mgemm_mlp2_kernel<<<dim3(1, (EL+127)/128, 1), 256, 0, stream>>>(
      out2b, eli, attr, mw1t, mb1, mw2, mb2, out, EL);
}